// Round 4
// baseline (5018.293 us; speedup 1.0000x reference)
//
#include <hip/hip_runtime.h>
#include <math.h>

#define KNN 30
#define SIGMA_N 0.8f
#define THRESHV 1e-3f

// ---- grid params ----
#define G 64
#define NC (G*G*G)
#define GLO (-5.2f)
#define GH  (10.4f / 64.0f)
#define INVGH (64.0f / 10.4f)

// ---- main-path tuning ----
#define LPQ 8          // lanes per query
#define QPB 32         // queries per block (256 threads)
#define CAPQ 456       // candidate cap per query
#define CAPSQ 457      // padded stride

// ws layout (bytes)
#define OFF_A     0u               // float4[M] sorted positions (w = |s|^2/2)
#define OFF_B     1048576u         // float4[M] sorted unit normals
#define OFF_CS    2097152u         // u32[NC+1] cellStart (source)
#define OFF_CUR   3145744u         // u32[NC] cursor (reused as query cursor)
#define OFF_PC    4194320u         // u32[max(M,N)] pointCell (reused for queries)
#define OFF_BS    4456464u         // u32[256] blockSums
#define OFF_QCS   4457488u         // u32[NC+1] query cellStart
#define OFF_QORD  5506080u         // u32[N] query order
#define WS_NEED   5637152u

// ======================= grid build =======================

__global__ void zero_u32(unsigned* __restrict__ p, int n) {
    int i = blockIdx.x * 256 + threadIdx.x;
    if (i < n) p[i] = 0u;
}

__device__ __forceinline__ int cell_of(float x, float y, float z) {
    int cx = (int)floorf((x - GLO) * INVGH);
    int cy = (int)floorf((y - GLO) * INVGH);
    int cz = (int)floorf((z - GLO) * INVGH);
    cx = min(max(cx, 0), G - 1);
    cy = min(max(cy, 0), G - 1);
    cz = min(max(cz, 0), G - 1);
    return (cz * G + cy) * G + cx;
}

__global__ void grid_count(const float* __restrict__ src, unsigned* __restrict__ counts,
                           unsigned* __restrict__ pointCell, int M) {
    int j = blockIdx.x * 256 + threadIdx.x;
    if (j >= M) return;
    int cell = cell_of(src[3*j+0], src[3*j+1], src[3*j+2]);
    pointCell[j] = (unsigned)cell;
    atomicAdd(&counts[cell], 1u);
}

__global__ void scan1(unsigned* __restrict__ cs, unsigned* __restrict__ blockSums) {
    __shared__ unsigned ts[256];
    int b = blockIdx.x, t = threadIdx.x;
    int base = b * 1024 + t * 4;
    unsigned c0 = cs[base], c1 = cs[base+1], c2 = cs[base+2], c3 = cs[base+3];
    unsigned s = c0 + c1 + c2 + c3;
    ts[t] = s;
    __syncthreads();
    for (int off = 1; off < 256; off <<= 1) {
        unsigned y = (t >= off) ? ts[t - off] : 0u;
        __syncthreads();
        ts[t] += y;
        __syncthreads();
    }
    unsigned ex = ts[t] - s;
    cs[base]   = ex;
    cs[base+1] = ex + c0;
    cs[base+2] = ex + c0 + c1;
    cs[base+3] = ex + c0 + c1 + c2;
    if (t == 255) blockSums[b] = ts[255];
}

__global__ void scan2(unsigned* __restrict__ blockSums) {
    __shared__ unsigned ts[256];
    int t = threadIdx.x;
    unsigned v = blockSums[t];
    ts[t] = v;
    __syncthreads();
    for (int off = 1; off < 256; off <<= 1) {
        unsigned y = (t >= off) ? ts[t - off] : 0u;
        __syncthreads();
        ts[t] += y;
        __syncthreads();
    }
    blockSums[t] = ts[t] - v;
}

__global__ void scan3(unsigned* __restrict__ cs, unsigned* __restrict__ cur,
                      const unsigned* __restrict__ blockSums, unsigned total) {
    int b = blockIdx.x, t = threadIdx.x;
    unsigned add = blockSums[b];
    int base = b * 1024 + t * 4;
    #pragma unroll
    for (int u = 0; u < 4; ++u) {
        unsigned v = cs[base + u] + add;
        cs[base + u] = v;
        cur[base + u] = v;
    }
    if (b == 255 && t == 255) cs[NC] = total;
}

__global__ void grid_scatter(const float* __restrict__ src, const float* __restrict__ snorms,
                             const unsigned* __restrict__ pointCell, unsigned* __restrict__ cur,
                             float4* __restrict__ A, float4* __restrict__ B, int M) {
    int j = blockIdx.x * 256 + threadIdx.x;
    if (j >= M) return;
    unsigned cell = pointCell[j];
    unsigned pos = atomicAdd(&cur[cell], 1u);
    float x = src[3*j+0], y = src[3*j+1], z = src[3*j+2];
    A[pos] = make_float4(x, y, z, 0.5f*(x*x + y*y + z*z));
    float nx = snorms[3*j+0], ny = snorms[3*j+1], nz = snorms[3*j+2];
    float nrm = sqrtf(nx*nx + ny*ny + nz*nz);
    float inv = 1.0f / fmaxf(nrm, 1e-8f);
    B[pos] = make_float4(nx*inv, ny*inv, nz*inv, 0.0f);
}

__global__ void qscatter(const unsigned* __restrict__ qpc, unsigned* __restrict__ qcur,
                         unsigned* __restrict__ qorder, int N) {
    int j = blockIdx.x * 256 + threadIdx.x;
    if (j >= N) return;
    unsigned pos = atomicAdd(&qcur[qpc[j]], 1u);
    qorder[pos] = (unsigned)j;
}

// ======================= search + epilogue =======================

__device__ __forceinline__ void ins4(unsigned k, unsigned &m0, unsigned &m1,
                                     unsigned &m2, unsigned &m3) {
    if (k < m3) {
        if (k < m2) {
            m3 = m2;
            if (k < m1) { m2 = m1; if (k < m0) { m1 = m0; m0 = k; } else m1 = k; }
            else m2 = k;
        } else m3 = k;
    }
}

__device__ __forceinline__ unsigned selectK(const unsigned* __restrict__ cq,
                                            unsigned C, int l) {
    unsigned lo = 0u, hi = 0xFFFFFFFFu;
    while (lo < hi) {
        unsigned mid = lo + ((hi - lo) >> 1);
        int c = 0;
        for (unsigned i = (unsigned)l; i < C; i += LPQ) c += (cq[i] <= mid) ? 1 : 0;
        c += __shfl_xor(c, 1, LPQ);
        c += __shfl_xor(c, 2, LPQ);
        c += __shfl_xor(c, 4, LPQ);
        if (c >= KNN) hi = mid; else lo = mid + 1;
    }
    return lo;   // exact 30th-smallest key (keys unique)
}

__device__ __forceinline__ void scan_cell8(const float4* __restrict__ A,
                                           unsigned st, unsigned en,
                                           float qx, float qy, float qz, float q2h,
                                           int l, unsigned* __restrict__ cq,
                                           unsigned* __restrict__ cntg,
                                           unsigned& filterKey,
                                           unsigned& m0, unsigned& m1,
                                           unsigned& m2, unsigned& m3) {
    for (unsigned base = st; base < en; base += LPQ) {
        unsigned p = base + (unsigned)l;
        if (p < en) {
            float4 sp = A[p];
            float v = fmaxf(fmaf(-qx, sp.x, fmaf(-qy, sp.y, fmaf(-qz, sp.z, sp.w + q2h))), 0.0f);
            unsigned key = (__float_as_uint(v) & 0xFFFF0000u) | p;
            if (key <= filterKey) {
                ins4(key, m0, m1, m2, m3);
                unsigned pos = atomicAdd(cntg, 1u);
                if (pos < (unsigned)CAPQ) cq[pos] = key;
            }
        }
        // certified filter: max over lanes of per-lane 4th-smallest (>=32 keys <= T)
        unsigned T = m3;
        T = max(T, (unsigned)__shfl_xor((int)T, 1, LPQ));
        T = max(T, (unsigned)__shfl_xor((int)T, 2, LPQ));
        T = max(T, (unsigned)__shfl_xor((int)T, 4, LPQ));
        filterKey = min(filterKey, T);
    }
}

__global__ __launch_bounds__(256)
void knn_rimls8(const float* __restrict__ qpts,
                const float4* __restrict__ A,
                const float4* __restrict__ B,
                const unsigned* __restrict__ cellStart,
                const unsigned* __restrict__ qorder,
                float* __restrict__ out, int N) {
    __shared__ unsigned cand[QPB * CAPSQ];   // 58,496 B
    __shared__ unsigned cnt[QPB];
    __shared__ unsigned selc[QPB];
    __shared__ unsigned selk[QPB * 32];      // 4096 B
    const int t = threadIdx.x;
    const int g = t >> 3;      // group (query slot in block)
    const int l = t & 7;       // lane within group
    if (l == 0) { cnt[g] = 0u; selc[g] = 0u; }
    __syncthreads();

    int slot = blockIdx.x * QPB + g;
    const int vq = (slot < N);
    const int gq = vq ? (int)qorder[slot] : 0;
    const float qx = qpts[3*gq+0], qy = qpts[3*gq+1], qz = qpts[3*gq+2];
    const float q2h = 0.5f*(qx*qx + qy*qy + qz*qz);
    int cx = (int)floorf((qx - GLO) * INVGH);
    int cy = (int)floorf((qy - GLO) * INVGH);
    int cz = (int)floorf((qz - GLO) * INVGH);
    cx = min(max(cx, 0), G - 1);
    cy = min(max(cy, 0), G - 1);
    cz = min(max(cz, 0), G - 1);

    unsigned* cq = cand + g * CAPSQ;
    unsigned filterKey = 0xFFFFFFFFu;
    unsigned m0 = ~0u, m1 = ~0u, m2 = ~0u, m3 = ~0u;
    int retries = 0;

    for (int s = 0; s < G; ++s) {
        // ---- scan ring s (group-cooperative) ----
        if (s == 0) {
            int cell = (cz * G + cy) * G + cx;
            scan_cell8(A, cellStart[cell], cellStart[cell+1], qx, qy, qz, q2h,
                       l, cq, &cnt[g], filterKey, m0, m1, m2, m3);
        } else {
            for (int dz = -s; dz <= s; ++dz) {
                int z = cz + dz; if ((unsigned)z >= (unsigned)G) continue;
                for (int dy = -s; dy <= s; ++dy) {
                    int y = cy + dy; if ((unsigned)y >= (unsigned)G) continue;
                    bool face = (dz == -s) || (dz == s) || (dy == -s) || (dy == s);
                    int step = face ? 1 : (2 * s);
                    for (int dx = -s; dx <= s; dx += step) {
                        int x = cx + dx; if ((unsigned)x >= (unsigned)G) continue;
                        int cell = (z * G + y) * G + x;
                        unsigned st = cellStart[cell], en = cellStart[cell+1];
                        if (st != en)
                            scan_cell8(A, st, en, qx, qy, qz, q2h,
                                       l, cq, &cnt[g], filterKey, m0, m1, m2, m3);
                    }
                }
            }
        }
        // ---- overflow? tighten to exact 30th-of-buffer (upper bound on true d30) & rescan ----
        unsigned cN = cnt[g];
        if (cN > (unsigned)CAPQ) {
            if (retries < 3) {
                ++retries;
                unsigned T30 = selectK(cq, (unsigned)CAPQ, l);
                filterKey = min(filterKey, T30);
                if (l == 0) cnt[g] = 0u;
                s = -1;
                continue;
            }
            cN = (unsigned)CAPQ;
        }
        // ---- certification: >=30 scanned points strictly inside ring boundary ----
        float b = 1e30f;
        if (cx + s + 1 <= G - 1) b = fminf(b, GLO + (float)(cx + s + 1) * GH - qx);
        if (cx - s - 1 >= 0)     b = fminf(b, qx - (GLO + (float)(cx - s) * GH));
        if (cy + s + 1 <= G - 1) b = fminf(b, GLO + (float)(cy + s + 1) * GH - qy);
        if (cy - s - 1 >= 0)     b = fminf(b, qy - (GLO + (float)(cy - s) * GH));
        if (cz + s + 1 <= G - 1) b = fminf(b, GLO + (float)(cz + s + 1) * GH - qz);
        if (cz - s - 1 >= 0)     b = fminf(b, qz - (GLO + (float)(cz - s) * GH));
        if (b >= 1e29f) break;                  // whole grid scanned
        b = fmaxf(b, 0.0f);
        unsigned bk = __float_as_uint(0.5f * b * b) >> 16;
        int cb = 0;
        for (unsigned i = (unsigned)l; i < cN; i += LPQ) cb += ((cq[i] >> 16) < bk) ? 1 : 0;
        cb += __shfl_xor(cb, 1, LPQ);
        cb += __shfl_xor(cb, 2, LPQ);
        cb += __shfl_xor(cb, 4, LPQ);
        if (cb >= KNN) break;
    }

    // ---- exact top-30 compaction ----
    unsigned Cv = cnt[g]; if (Cv > (unsigned)CAPQ) Cv = (unsigned)CAPQ;
    unsigned T30 = (Cv > (unsigned)KNN) ? selectK(cq, Cv, l) : 0xFFFFFFFFu;
    for (unsigned i = (unsigned)l; i < Cv; i += LPQ) {
        unsigned k = cq[i];
        if (k <= T30) {
            unsigned pos = atomicAdd(&selc[g], 1u);
            if (pos < 32u) selk[g*32 + pos] = k;
        }
    }
    unsigned sc = selc[g]; if (sc > (unsigned)KNN) sc = (unsigned)KNN;

    // ---- epilogue: neighbor statics in registers (4 slots/lane) ----
    float px_[4], py_[4], pz_[4], nx_[4], ny_[4], nz_[4];
    float fx_[4], phi_[4], gco_[4], r2_[4];
    float dsum = 0.0f;
    #pragma unroll
    for (int u = 0; u < 4; ++u) {
        int k = l + 8*u;
        bool v = (k < (int)sc);
        int j = v ? (int)(selk[g*32 + k] & 0xFFFFu) : 0;
        float4 sp = A[j];
        float4 nn = B[j];
        float px = qx - sp.x, py = qy - sp.y, pz = qz - sp.z;
        float r2 = px*px + py*py + pz*pz;
        float m = v ? 1.0f : 0.0f;
        px_[u] = px * m; py_[u] = py * m; pz_[u] = pz * m;
        nx_[u] = nn.x * m; ny_[u] = nn.y * m; nz_[u] = nn.z * m;
        r2_[u] = r2 * m;
        fx_[u] = px_[u]*nx_[u] + py_[u]*ny_[u] + pz_[u]*nz_[u];
        dsum += v ? sqrtf(r2) : 0.0f;
        phi_[u] = m;   // validity; fixed after h known
    }
    dsum += __shfl_xor(dsum, 1, LPQ);
    dsum += __shfl_xor(dsum, 2, LPQ);
    dsum += __shfl_xor(dsum, 4, LPQ);
    float h = dsum * (1.0f / (float)KNN) + 1e-8f;
    float h2 = h * h;
    float c8 = -8.0f / h2;
    #pragma unroll
    for (int u = 0; u < 4; ++u) {
        float tt = fmaxf(1.0f - r2_[u] / h2, 0.0f);
        float t2 = tt * tt;
        float valid = phi_[u];
        phi_[u] = t2 * t2 * valid;
        gco_[u] = c8 * t2 * tt * valid;
    }

    const float inv_sn2 = 1.0f / (SIGMA_N * SIGMA_N);
    float f = 0.0f, gx = 0.0f, gy = 0.0f, gz = 0.0f;
    bool done = false;
    for (int it = 0; it < 3; ++it) {
        if (done) break;
        float sw=0, swf=0, sgx=0, sgy=0, sgz=0, sfx=0, sfy=0, sfz=0, snx=0, sny=0, snz=0;
        #pragma unroll
        for (int u = 0; u < 4; ++u) {
            float alpha = 1.0f;
            if (it > 0) {
                float dx = nx_[u]-gx, dy = ny_[u]-gy, dz = nz_[u]-gz;
                alpha = expf(-(dx*dx + dy*dy + dz*dz) * inv_sn2);
            }
            float w = alpha * phi_[u];
            float gg = alpha * gco_[u];
            float gf = gg * fx_[u];
            sw  += w;          swf += w * fx_[u];
            sgx += gg*px_[u];  sgy += gg*py_[u];  sgz += gg*pz_[u];
            sfx += gf*px_[u];  sfy += gf*py_[u];  sfz += gf*pz_[u];
            snx += w*nx_[u];   sny += w*ny_[u];   snz += w*nz_[u];
        }
        #pragma unroll
        for (int m = 1; m < LPQ; m <<= 1) {
            sw  += __shfl_xor(sw, m, LPQ);  swf += __shfl_xor(swf, m, LPQ);
            sgx += __shfl_xor(sgx, m, LPQ); sgy += __shfl_xor(sgy, m, LPQ); sgz += __shfl_xor(sgz, m, LPQ);
            sfx += __shfl_xor(sfx, m, LPQ); sfy += __shfl_xor(sfy, m, LPQ); sfz += __shfl_xor(sfz, m, LPQ);
            snx += __shfl_xor(snx, m, LPQ); sny += __shfl_xor(sny, m, LPQ); snz += __shfl_xor(snz, m, LPQ);
        }
        sw += 1e-8f;
        float fn  = swf / sw;
        float gnx = (sfx + snx - fn*sgx) / sw;
        float gny = (sfy + sny - fn*sgy) / sw;
        float gnz = (sfz + snz - fn*sgz) / sw;
        done = (fabsf(fn - f) < THRESHV);
        f = fn; gx = gnx; gy = gny; gz = gnz;
    }
    if (l == 0 && vq) {
        out[gq] = f;
        out[N + 3*gq + 0] = gx;
        out[N + 3*gq + 1] = gy;
        out[N + 3*gq + 2] = gz;
    }
}

// ======================= fallback: R2 brute force =======================

#define QT 32
#define NTH 256
#define CAP 160
#define CAPS 161
#define RSEL 20

__global__ void prep_pack(const float* __restrict__ src, float4* __restrict__ dst, int M) {
    int j = blockIdx.x * 256 + threadIdx.x;
    if (j < M) {
        float x = src[3*j+0], y = src[3*j+1], z = src[3*j+2];
        dst[j] = make_float4(x, y, z, 0.5f*(x*x + y*y + z*z));
    }
}

template<bool PACKED>
__device__ __forceinline__ float4 fetch_pt(const float4* __restrict__ sp,
                                           const float* __restrict__ sv, int j) {
    if (PACKED) return sp[j];
    float x = sv[3*j+0], y = sv[3*j+1], z = sv[3*j+2];
    return make_float4(x, y, z, 0.5f*(x*x + y*y + z*z));
}

template<bool PACKED>
__global__ __launch_bounds__(NTH)
void rimls_fused(const float* __restrict__ qpts,
                 const float* __restrict__ sverts,
                 const float* __restrict__ snorms,
                 const float4* __restrict__ spack,
                 float* __restrict__ out,
                 int N, int M)
{
    __shared__ unsigned int cand[QT * CAPS];
    __shared__ unsigned int selk[QT * KNN];
    __shared__ float4 qbuf[QT];
    __shared__ unsigned int cnt[QT];
    __shared__ unsigned int T16[QT];
    __shared__ int retryq[QT];

    const int t  = threadIdx.x;
    const int qg = t >> 4;
    const int c  = t & 15;
    const int qa = qg, qb = qg + 16;

    if (t < QT) {
        int gq = blockIdx.x * QT + t; if (gq >= N) gq = N - 1;
        float x = qpts[3*gq+0], y = qpts[3*gq+1], z = qpts[3*gq+2];
        qbuf[t] = make_float4(x, y, z, 0.5f*(x*x + y*y + z*z));
    }
    for (int i = t; i < QT * KNN; i += NTH) selk[i] = 0u;
    __syncthreads();

    const float ax = qbuf[qa].x, ay = qbuf[qa].y, az = qbuf[qa].z, aw = qbuf[qa].w;
    const float bx = qbuf[qb].x, by = qbuf[qb].y, bz = qbuf[qb].z, bw = qbuf[qb].w;

    unsigned int a0=~0u,a1=~0u,a2=~0u,a3=~0u, b0=~0u,b1=~0u,b2=~0u,b3=~0u;
    {
        const int n1 = M >> 6;
        #pragma unroll 2
        for (int i = 0; i < n1; ++i) {
            int j = (c + (i << 4)) << 2;
            float4 s = fetch_pt<PACKED>(spack, sverts, j);
            float va = fmaxf(fmaf(-ax, s.x, fmaf(-ay, s.y, fmaf(-az, s.z, s.w + aw))), 0.0f);
            float vb = fmaxf(fmaf(-bx, s.x, fmaf(-by, s.y, fmaf(-bz, s.z, s.w + bw))), 0.0f);
            unsigned int ka = (__float_as_uint(va) & 0xFFFF0000u) | (unsigned int)j;
            unsigned int kb = (__float_as_uint(vb) & 0xFFFF0000u) | (unsigned int)j;
            ins4(ka, a0, a1, a2, a3);
            ins4(kb, b0, b1, b2, b3);
        }
    }
    {
        unsigned int* mb = cand;
        mb[qa*64 + c*4 + 0] = a0; mb[qa*64 + c*4 + 1] = a1;
        mb[qa*64 + c*4 + 2] = a2; mb[qa*64 + c*4 + 3] = a3;
        mb[qb*64 + c*4 + 0] = b0; mb[qb*64 + c*4 + 1] = b1;
        mb[qb*64 + c*4 + 2] = b2; mb[qb*64 + c*4 + 3] = b3;
    }
    __syncthreads();
    if (t < QT) {
        const unsigned int* m_ = cand + t * 64;
        unsigned int kth = 0xFFFFFFFFu;
        for (int a = 0; a < 64; ++a) {
            unsigned int ka = m_[a]; int r = 0;
            for (int b = 0; b < 64; ++b) r += (m_[b] < ka) ? 1 : 0;
            if (r == RSEL - 1) kth = ka;
        }
        unsigned int tb = (kth >> 16) + 1u;
        if (tb > 0x7F00u) tb = 0x7F00u;
        T16[t] = tb; cnt[t] = 0u; retryq[t] = 1;
    }
    __syncthreads();

    const int n3 = M >> 4;
    for (int round = 0; round < 8; ++round) {
        bool aa = retryq[qa] != 0, ab = retryq[qb] != 0;
        if (aa || ab) {
            float Ta = aa ? __uint_as_float(T16[qa] << 16) : 0.0f;
            float Tb = ab ? __uint_as_float(T16[qb] << 16) : 0.0f;
            #pragma unroll 4
            for (int i = 0; i < n3; ++i) {
                int j = c + (i << 4);
                float4 s = fetch_pt<PACKED>(spack, sverts, j);
                float va = fmaxf(fmaf(-ax, s.x, fmaf(-ay, s.y, fmaf(-az, s.z, s.w + aw))), 0.0f);
                float vb = fmaxf(fmaf(-bx, s.x, fmaf(-by, s.y, fmaf(-bz, s.z, s.w + bw))), 0.0f);
                if (va < Ta) {
                    unsigned int pos = atomicAdd(&cnt[qa], 1u);
                    if (pos < (unsigned)CAP)
                        cand[qa*CAPS + pos] = (__float_as_uint(va) & 0xFFFF0000u) | (unsigned int)j;
                }
                if (vb < Tb) {
                    unsigned int pos = atomicAdd(&cnt[qb], 1u);
                    if (pos < (unsigned)CAP)
                        cand[qb*CAPS + pos] = (__float_as_uint(vb) & 0xFFFF0000u) | (unsigned int)j;
                }
            }
        }
        __syncthreads();
        int bad = 0;
        if (t < QT && retryq[t]) {
            unsigned int cc = cnt[t], tb = T16[t];
            if (cc < (unsigned)KNN) {
                if (tb < 0x7F00u) {
                    tb += (1u << 7);
                    if (tb > 0x7F00u) tb = 0x7F00u;
                    bad = 1;
                }
            } else if (cc > (unsigned)CAP && round < 4 && tb > (1u << 6)) {
                tb -= (1u << 6); bad = 1;
            }
            if (bad) { T16[t] = tb; cnt[t] = 0u; }
            else retryq[t] = 0;
        }
        if (!__syncthreads_or(bad)) break;
    }

    const int qs = t >> 3, s8 = t & 7;
    {
        unsigned int cc = cnt[qs];
        int C = (int)(cc < (unsigned)CAP ? cc : (unsigned)CAP);
        const unsigned int* cd = cand + qs * CAPS;
        for (int a = s8; a < C; a += 8) {
            unsigned int ka = cd[a]; int r = 0;
            for (int b = 0; b < C; ++b) r += (cd[b] < ka) ? 1 : 0;
            if (r < KNN) selk[qs*KNN + r] = ka;
        }
    }
    __syncthreads();

    {
        const float qx = qbuf[qs].x, qy = qbuf[qs].y, qz = qbuf[qs].z;
        float px_[4], py_[4], pz_[4], nx_[4], ny_[4], nz_[4];
        float fx_[4], phi_[4], gco_[4], r2_[4];
        float dsum = 0.0f;
        #pragma unroll
        for (int u = 0; u < 4; ++u) {
            int k = s8 + 8*u;
            bool v = (k < KNN);
            int j = v ? (int)(selk[qs*KNN + k] & 0xFFFFu) : 0;
            float4 s = fetch_pt<PACKED>(spack, sverts, j);
            float px = qx - s.x, py = qy - s.y, pz = qz - s.z;
            float r2 = px*px + py*py + pz*pz;
            float nx = snorms[3*j+0], ny = snorms[3*j+1], nz = snorms[3*j+2];
            float nrm = sqrtf(nx*nx + ny*ny + nz*nz);
            float inv = 1.0f / fmaxf(nrm, 1e-8f);
            float m = v ? 1.0f : 0.0f;
            nx *= inv * m; ny *= inv * m; nz *= inv * m;
            px_[u] = px * m; py_[u] = py * m; pz_[u] = pz * m;
            nx_[u] = nx; ny_[u] = ny; nz_[u] = nz;
            r2_[u] = r2 * m;
            fx_[u] = px_[u]*nx + py_[u]*ny + pz_[u]*nz;
            dsum += v ? sqrtf(r2) : 0.0f;
            phi_[u] = m;
        }
        dsum += __shfl_xor(dsum, 1);
        dsum += __shfl_xor(dsum, 2);
        dsum += __shfl_xor(dsum, 4);
        float h = dsum * (1.0f / (float)KNN) + 1e-8f;
        float h2 = h * h;
        float c8 = -8.0f / h2;
        #pragma unroll
        for (int u = 0; u < 4; ++u) {
            float tt = fmaxf(1.0f - r2_[u] / h2, 0.0f);
            float t2 = tt * tt;
            float valid = phi_[u];
            phi_[u] = t2 * t2 * valid;
            gco_[u] = c8 * t2 * tt * valid;
        }

        const float inv_sn2 = 1.0f / (SIGMA_N * SIGMA_N);
        float f = 0.0f, gx = 0.0f, gy = 0.0f, gz = 0.0f;
        bool done = false;
        for (int it = 0; it < 3; ++it) {
            if (done) break;
            float sw=0, swf=0, sgx=0, sgy=0, sgz=0, sfx=0, sfy=0, sfz=0, snx=0, sny=0, snz=0;
            #pragma unroll
            for (int u = 0; u < 4; ++u) {
                float alpha = 1.0f;
                if (it > 0) {
                    float dx = nx_[u]-gx, dy = ny_[u]-gy, dz = nz_[u]-gz;
                    alpha = expf(-(dx*dx + dy*dy + dz*dz) * inv_sn2);
                }
                float w = alpha * phi_[u];
                float g = alpha * gco_[u];
                float gf = g * fx_[u];
                sw  += w;          swf += w * fx_[u];
                sgx += g*px_[u];   sgy += g*py_[u];   sgz += g*pz_[u];
                sfx += gf*px_[u];  sfy += gf*py_[u];  sfz += gf*pz_[u];
                snx += w*nx_[u];   sny += w*ny_[u];   snz += w*nz_[u];
            }
            #pragma unroll
            for (int m = 1; m < 8; m <<= 1) {
                sw  += __shfl_xor(sw, m);  swf += __shfl_xor(swf, m);
                sgx += __shfl_xor(sgx, m); sgy += __shfl_xor(sgy, m); sgz += __shfl_xor(sgz, m);
                sfx += __shfl_xor(sfx, m); sfy += __shfl_xor(sfy, m); sfz += __shfl_xor(sfz, m);
                snx += __shfl_xor(snx, m); sny += __shfl_xor(sny, m); snz += __shfl_xor(snz, m);
            }
            sw += 1e-8f;
            float fn  = swf / sw;
            float gnx = (sfx + snx - fn*sgx) / sw;
            float gny = (sfy + sny - fn*sgy) / sw;
            float gnz = (sfz + snz - fn*sgz) / sw;
            float delta = fabsf(fn - f);
            f = fn; gx = gnx; gy = gny; gz = gnz;
            done = (delta < THRESHV);
        }
        if (s8 == 0) {
            int gq = blockIdx.x * QT + qs;
            if (gq < N) {
                out[gq] = f;
                out[N + 3*gq + 0] = gx;
                out[N + 3*gq + 1] = gy;
                out[N + 3*gq + 2] = gz;
            }
        }
    }
}

// ======================= launcher =======================

extern "C" void kernel_launch(void* const* d_in, const int* in_sizes, int n_in,
                              void* d_out, int out_size, void* d_ws, size_t ws_size,
                              hipStream_t stream) {
    (void)n_in; (void)out_size;
    const float* qpts   = (const float*)d_in[0];
    const float* sverts = (const float*)d_in[1];
    const float* snorms = (const float*)d_in[2];
    float* out = (float*)d_out;
    int N = in_sizes[0] / 3;
    int M = in_sizes[1] / 3;

    if (ws_size >= (size_t)WS_NEED && M <= 65536 && N <= 65536) {
        char* ws = (char*)d_ws;
        float4*   A    = (float4*)(ws + OFF_A);
        float4*   B    = (float4*)(ws + OFF_B);
        unsigned* cs   = (unsigned*)(ws + OFF_CS);
        unsigned* cur  = (unsigned*)(ws + OFF_CUR);   // reused as query cursor
        unsigned* pc   = (unsigned*)(ws + OFF_PC);    // reused as query pointCell
        unsigned* bs   = (unsigned*)(ws + OFF_BS);
        unsigned* qcs  = (unsigned*)(ws + OFF_QCS);
        unsigned* qord = (unsigned*)(ws + OFF_QORD);

        // source grid
        zero_u32<<<(NC + 1 + 255) / 256, 256, 0, stream>>>(cs, NC + 1);
        grid_count<<<(M + 255) / 256, 256, 0, stream>>>(sverts, cs, pc, M);
        scan1<<<256, 256, 0, stream>>>(cs, bs);
        scan2<<<1, 256, 0, stream>>>(bs);
        scan3<<<256, 256, 0, stream>>>(cs, cur, bs, (unsigned)M);
        grid_scatter<<<(M + 255) / 256, 256, 0, stream>>>(sverts, snorms, pc, cur, A, B, M);
        // query sort by cell (cur/pc/bs reused after source build)
        zero_u32<<<(NC + 1 + 255) / 256, 256, 0, stream>>>(qcs, NC + 1);
        grid_count<<<(N + 255) / 256, 256, 0, stream>>>(qpts, qcs, pc, N);
        scan1<<<256, 256, 0, stream>>>(qcs, bs);
        scan2<<<1, 256, 0, stream>>>(bs);
        scan3<<<256, 256, 0, stream>>>(qcs, cur, bs, (unsigned)N);
        qscatter<<<(N + 255) / 256, 256, 0, stream>>>(pc, cur, qord, N);
        // fused search + epilogue
        knn_rimls8<<<(N + QPB - 1) / QPB, 256, 0, stream>>>(qpts, A, B, cs, qord, out, N);
    } else if (ws_size >= (size_t)M * sizeof(float4)) {
        float4* spack = (float4*)d_ws;
        prep_pack<<<(M + 255) / 256, 256, 0, stream>>>(sverts, spack, M);
        rimls_fused<true><<<(N + QT - 1) / QT, NTH, 0, stream>>>(qpts, sverts, snorms, spack, out, N, M);
    } else {
        rimls_fused<false><<<(N + QT - 1) / QT, NTH, 0, stream>>>(qpts, sverts, snorms, nullptr, out, N, M);
    }
}

// Round 6
// 2234.667 us; speedup vs baseline: 2.2457x; 2.2457x over previous
//
#include <hip/hip_runtime.h>
#include <math.h>

#define KNN 30
#define SIGMA_N 0.8f
#define THRESHV 1e-3f

// ---- grid params ----
#define G 64
#define NC (G*G*G)
#define GLO (-5.2f)
#define GH  (10.4f / 64.0f)
#define INVGH (64.0f / 10.4f)

// ---- main search tuning ----
#define LPQ 4          // lanes per query
#define QPB 64         // queries per block (256 threads)
#define CAPL 64        // per-lane candidate segment capacity

// ws layout (bytes)
#define OFF_A     0u               // float4[M] sorted positions (w = |s|^2/2)
#define OFF_B     1048576u         // float4[M] sorted unit normals
#define OFF_CS    2097152u         // u32[NC+1] cellStart (source)
#define OFF_CUR   3145744u         // u32[NC] cursor (reused as query cursor)
#define OFF_PC    4194320u         // u32[max(M,N)] pointCell (reused for queries)
#define OFF_BS    4456464u         // u32[256] blockSums
#define OFF_QCS   4457488u         // u32[NC+1] query cellStart
#define OFF_QORD  5506080u         // u32[N] query order
#define WS_NEED   5637152u

// ======================= grid build =======================

__global__ void zero_u32(unsigned* __restrict__ p, int n) {
    int i = blockIdx.x * 256 + threadIdx.x;
    if (i < n) p[i] = 0u;
}

__device__ __forceinline__ int cell_of(float x, float y, float z) {
    int cx = (int)floorf((x - GLO) * INVGH);
    int cy = (int)floorf((y - GLO) * INVGH);
    int cz = (int)floorf((z - GLO) * INVGH);
    cx = min(max(cx, 0), G - 1);
    cy = min(max(cy, 0), G - 1);
    cz = min(max(cz, 0), G - 1);
    return (cz * G + cy) * G + cx;
}

__global__ void grid_count(const float* __restrict__ src, unsigned* __restrict__ counts,
                           unsigned* __restrict__ pointCell, int M) {
    int j = blockIdx.x * 256 + threadIdx.x;
    if (j >= M) return;
    int cell = cell_of(src[3*j+0], src[3*j+1], src[3*j+2]);
    pointCell[j] = (unsigned)cell;
    atomicAdd(&counts[cell], 1u);
}

__global__ void scan1(unsigned* __restrict__ cs, unsigned* __restrict__ blockSums) {
    __shared__ unsigned ts[256];
    int b = blockIdx.x, t = threadIdx.x;
    int base = b * 1024 + t * 4;
    unsigned c0 = cs[base], c1 = cs[base+1], c2 = cs[base+2], c3 = cs[base+3];
    unsigned s = c0 + c1 + c2 + c3;
    ts[t] = s;
    __syncthreads();
    for (int off = 1; off < 256; off <<= 1) {
        unsigned y = (t >= off) ? ts[t - off] : 0u;
        __syncthreads();
        ts[t] += y;
        __syncthreads();
    }
    unsigned ex = ts[t] - s;
    cs[base]   = ex;
    cs[base+1] = ex + c0;
    cs[base+2] = ex + c0 + c1;
    cs[base+3] = ex + c0 + c1 + c2;
    if (t == 255) blockSums[b] = ts[255];
}

__global__ void scan2(unsigned* __restrict__ blockSums) {
    __shared__ unsigned ts[256];
    int t = threadIdx.x;
    unsigned v = blockSums[t];
    ts[t] = v;
    __syncthreads();
    for (int off = 1; off < 256; off <<= 1) {
        unsigned y = (t >= off) ? ts[t - off] : 0u;
        __syncthreads();
        ts[t] += y;
        __syncthreads();
    }
    blockSums[t] = ts[t] - v;
}

__global__ void scan3(unsigned* __restrict__ cs, unsigned* __restrict__ cur,
                      const unsigned* __restrict__ blockSums, unsigned total) {
    int b = blockIdx.x, t = threadIdx.x;
    unsigned add = blockSums[b];
    int base = b * 1024 + t * 4;
    #pragma unroll
    for (int u = 0; u < 4; ++u) {
        unsigned v = cs[base + u] + add;
        cs[base + u] = v;
        cur[base + u] = v;
    }
    if (b == 255 && t == 255) cs[NC] = total;
}

__global__ void grid_scatter(const float* __restrict__ src, const float* __restrict__ snorms,
                             const unsigned* __restrict__ pointCell, unsigned* __restrict__ cur,
                             float4* __restrict__ A, float4* __restrict__ B, int M) {
    int j = blockIdx.x * 256 + threadIdx.x;
    if (j >= M) return;
    unsigned cell = pointCell[j];
    unsigned pos = atomicAdd(&cur[cell], 1u);
    float x = src[3*j+0], y = src[3*j+1], z = src[3*j+2];
    A[pos] = make_float4(x, y, z, 0.5f*(x*x + y*y + z*z));
    float nx = snorms[3*j+0], ny = snorms[3*j+1], nz = snorms[3*j+2];
    float nrm = sqrtf(nx*nx + ny*ny + nz*nz);
    float inv = 1.0f / fmaxf(nrm, 1e-8f);
    B[pos] = make_float4(nx*inv, ny*inv, nz*inv, 0.0f);
}

__global__ void qscatter(const unsigned* __restrict__ qpc, unsigned* __restrict__ qcur,
                         unsigned* __restrict__ qorder, int N) {
    int j = blockIdx.x * 256 + threadIdx.x;
    if (j >= N) return;
    unsigned pos = atomicAdd(&qcur[qpc[j]], 1u);
    qorder[pos] = (unsigned)j;
}

// ======================= search + epilogue =======================

// insert into ascending sorted 8-reg list, dropping old max
__device__ __forceinline__ void ins8(unsigned k,
    unsigned &f0, unsigned &f1, unsigned &f2, unsigned &f3,
    unsigned &f4, unsigned &f5, unsigned &f6, unsigned &f7) {
    if (k < f7) {
        f7 = k; unsigned t;
        if (f7 < f6) { t = f6; f6 = f7; f7 = t; }
        if (f6 < f5) { t = f5; f5 = f6; f6 = t; }
        if (f5 < f4) { t = f4; f4 = f5; f5 = t; }
        if (f4 < f3) { t = f3; f3 = f4; f4 = t; }
        if (f3 < f2) { t = f2; f2 = f3; f3 = t; }
        if (f2 < f1) { t = f1; f1 = f2; f2 = t; }
        if (f1 < f0) { t = f0; f0 = f1; f1 = t; }
    }
}

// exact 30th-smallest over the group's 4 segments (binary search on key space)
// precondition: count over segments of (key <= hi0) >= KNN
__device__ __forceinline__ unsigned selT30(const unsigned* __restrict__ mseg, int cntl,
                                           unsigned hi0) {
    unsigned lo = 0u, hi = hi0;
    while (lo < hi) {
        unsigned mid = lo + ((hi - lo) >> 1);
        int c = 0;
        for (int i = 0; i < cntl; ++i) c += (mseg[i] <= mid) ? 1 : 0;
        c += __shfl_xor(c, 1, LPQ);
        c += __shfl_xor(c, 2, LPQ);
        if (c >= KNN) hi = mid; else lo = mid + 1;
    }
    return lo;
}

// scan one contiguous point range [st,en), 4-lane interleaved, filter-synced
__device__ __forceinline__ void scan_range(const float4* __restrict__ A,
    unsigned st, unsigned en, int l,
    float qx, float qy, float qz, float q2h,
    unsigned &filter, int &cntl, int &dropped, unsigned* __restrict__ mseg,
    unsigned &f0, unsigned &f1, unsigned &f2, unsigned &f3,
    unsigned &f4, unsigned &f5, unsigned &f6, unsigned &f7) {
    for (unsigned base = st; base < en; base += 2*LPQ) {
        unsigned pA = base + (unsigned)l;
        unsigned pB = pA + LPQ;
        if (pA < en) {
            float4 sp = A[pA];
            float v = fmaxf(fmaf(-qx, sp.x, fmaf(-qy, sp.y, fmaf(-qz, sp.z, sp.w + q2h))), 0.0f);
            unsigned key = (__float_as_uint(v) & 0xFFFF0000u) | pA;
            if (key <= filter) {
                ins8(key, f0,f1,f2,f3,f4,f5,f6,f7);
                if (cntl < CAPL) mseg[cntl++] = key; else dropped = 1;
            }
        }
        if (pB < en) {
            float4 sp = A[pB];
            float v = fmaxf(fmaf(-qx, sp.x, fmaf(-qy, sp.y, fmaf(-qz, sp.z, sp.w + q2h))), 0.0f);
            unsigned key = (__float_as_uint(v) & 0xFFFF0000u) | pB;
            if (key <= filter) {
                ins8(key, f0,f1,f2,f3,f4,f5,f6,f7);
                if (cntl < CAPL) mseg[cntl++] = key; else dropped = 1;
            }
        }
        unsigned T = f7;
        T = max(T, (unsigned)__shfl_xor((int)T, 1, LPQ));
        T = max(T, (unsigned)__shfl_xor((int)T, 2, LPQ));
        filter = min(filter, T);
    }
}

__global__ __launch_bounds__(256)
void knn_rimls4(const float* __restrict__ qpts,
                const float4* __restrict__ A,
                const float4* __restrict__ B,
                const unsigned* __restrict__ cellStart,
                const unsigned* __restrict__ qorder,
                float* __restrict__ out, int N) {
    __shared__ unsigned seg[QPB * LPQ * CAPL];   // 65,536 B (lane-private segments)
    __shared__ unsigned selk[QPB * 32];          // 8,192 B
    __shared__ unsigned selc[QPB];
    __shared__ unsigned t30s[QPB];
    const int t = threadIdx.x;
    const int g = t >> 2;
    const int l = t & 3;
    if (l == 0) { selc[g] = 0u; t30s[g] = 0xFFFFFFFFu; }
    __syncthreads();

    int slot = blockIdx.x * QPB + g;
    const int vq = (slot < N);
    const int gq = (int)qorder[vq ? slot : (N - 1)];
    const float qx = qpts[3*gq+0], qy = qpts[3*gq+1], qz = qpts[3*gq+2];
    const float q2h = 0.5f*(qx*qx + qy*qy + qz*qz);
    int cx = (int)floorf((qx - GLO) * INVGH);
    int cy = (int)floorf((qy - GLO) * INVGH);
    int cz = (int)floorf((qz - GLO) * INVGH);
    cx = min(max(cx, 0), G - 1);
    cy = min(max(cy, 0), G - 1);
    cz = min(max(cz, 0), G - 1);

    unsigned* mseg = seg + (g * LPQ + l) * CAPL;
    unsigned filter = 0xFFFFFFFFu;
    int cntl = 0;

    for (int attempt = 0; attempt < 3; ++attempt) {
        unsigned f0=~0u,f1=~0u,f2=~0u,f3=~0u,f4=~0u,f5=~0u,f6=~0u,f7=~0u;
        cntl = 0;
        int dropped = 0;

        for (int s = 0; s < G; ++s) {
            if (s == 0) {
                int c0 = (cz * G + cy) * G + cx;
                unsigned st = cellStart[c0], en = cellStart[c0 + 1];
                scan_range(A, st, en, l, qx, qy, qz, q2h,
                           filter, cntl, dropped, mseg, f0,f1,f2,f3,f4,f5,f6,f7);
            } else {
                for (int dz = -s; dz <= s; ++dz) {
                    int z = cz + dz; if ((unsigned)z >= (unsigned)G) continue;
                    bool zface = (dz == -s) || (dz == s);
                    for (int dy = -s; dy <= s; ++dy) {
                        int y = cy + dy; if ((unsigned)y >= (unsigned)G) continue;
                        int rowbase = (z * G + y) * G;
                        if (zface || dy == -s || dy == s) {
                            int x0 = max(cx - s, 0), x1 = min(cx + s, G - 1);
                            unsigned st = cellStart[rowbase + x0];
                            unsigned en = cellStart[rowbase + x1 + 1];
                            if (st != en)
                                scan_range(A, st, en, l, qx, qy, qz, q2h,
                                           filter, cntl, dropped, mseg, f0,f1,f2,f3,f4,f5,f6,f7);
                        } else {
                            int xl = cx - s, xr = cx + s;
                            bool vl = (xl >= 0), vr = (xr <= G - 1);
                            unsigned stl = 0, enl = 0, str = 0, enr = 0;
                            if (vl) { stl = cellStart[rowbase + xl]; enl = cellStart[rowbase + xl + 1]; }
                            if (vr) { str = cellStart[rowbase + xr]; enr = cellStart[rowbase + xr + 1]; }
                            if (vl && stl != enl)
                                scan_range(A, stl, enl, l, qx, qy, qz, q2h,
                                           filter, cntl, dropped, mseg, f0,f1,f2,f3,f4,f5,f6,f7);
                            if (vr && str != enr)
                                scan_range(A, str, enr, l, qx, qy, qz, q2h,
                                           filter, cntl, dropped, mseg, f0,f1,f2,f3,f4,f5,f6,f7);
                        }
                    }
                }
            }
            // ---- certification ----
            float b = 1e30f;
            if (cx + s + 1 <= G - 1) b = fminf(b, GLO + (float)(cx + s + 1) * GH - qx);
            if (cx - s - 1 >= 0)     b = fminf(b, qx - (GLO + (float)(cx - s) * GH));
            if (cy + s + 1 <= G - 1) b = fminf(b, GLO + (float)(cy + s + 1) * GH - qy);
            if (cy - s - 1 >= 0)     b = fminf(b, qy - (GLO + (float)(cy - s) * GH));
            if (cz + s + 1 <= G - 1) b = fminf(b, GLO + (float)(cz + s + 1) * GH - qz);
            if (cz - s - 1 >= 0)     b = fminf(b, qz - (GLO + (float)(cz - s) * GH));
            if (b >= 1e29f) break;                  // whole grid scanned
            b = fmaxf(b, 0.0f);
            unsigned bk = __float_as_uint(0.5f * b * b) >> 16;
            if ((filter >> 16) < bk) break;         // >=32 keys strictly inside boundary
            int cb = 0;
            for (int i = 0; i < cntl; ++i) cb += ((mseg[i] >> 16) < bk) ? 1 : 0;
            cb += __shfl_xor(cb, 1, LPQ);
            cb += __shfl_xor(cb, 2, LPQ);
            if (cb >= KNN) break;
        }

        int dr = dropped;
        dr |= __shfl_xor(dr, 1, LPQ);
        dr |= __shfl_xor(dr, 2, LPQ);
        if (!dr || attempt == 2) {
            // stash top-8 regs for selection (ALWAYS on final attempt)
            unsigned* sb = selk + g * 32 + l * 8;
            sb[0]=f0; sb[1]=f1; sb[2]=f2; sb[3]=f3; sb[4]=f4; sb[5]=f5; sb[6]=f6; sb[7]=f7;
            break;
        }
        // rare: tighten filter to (>= true T30) and redo walk
        filter = min(filter, selT30(mseg, cntl, filter));
    }

    // ---- T30: stash rank-pass shortcut, validated two-sided, exact fallback ----
    {
        unsigned myf[8];
        #pragma unroll
        for (int i = 0; i < 8; ++i) myf[i] = selk[g*32 + l*8 + i];
        int r[8];
        #pragma unroll
        for (int i = 0; i < 8; ++i) r[i] = 0;
        for (int j = 0; j < 32; ++j) {
            unsigned kj = selk[g*32 + j];
            #pragma unroll
            for (int i = 0; i < 8; ++i) r[i] += (kj < myf[i]) ? 1 : 0;
        }
        #pragma unroll
        for (int i = 0; i < 8; ++i) if (r[i] == KNN - 1) t30s[g] = myf[i];
        unsigned T30 = t30s[g];
        // two-sided validation: T30 is correct iff EXACTLY 30 segment keys <= T30
        int cb = 0;
        for (int i = 0; i < cntl; ++i) cb += (mseg[i] <= T30) ? 1 : 0;
        cb += __shfl_xor(cb, 1, LPQ);
        cb += __shfl_xor(cb, 2, LPQ);
        if (cb != KNN) {
            // exact: binary search over [0, filter]; filter >= 32nd-smallest >= c30,
            // and >=32 segment keys <= filter, so this converges to the true 30th key.
            T30 = selT30(mseg, cntl, filter);
        }
        for (int i = 0; i < cntl; ++i) {
            unsigned k = mseg[i];
            if (k <= T30) {
                unsigned pos = atomicAdd(&selc[g], 1u);
                if (pos < 32u) selk[g*32 + pos] = k;
            }
        }
    }
    unsigned sc = selc[g]; if (sc > (unsigned)KNN) sc = (unsigned)KNN;

    // ---- epilogue: statics in registers, 8 slots/lane ----
    float px_[8], py_[8], pz_[8], nx_[8], ny_[8], nz_[8], fx_[8], phi_[8], gco_[8], r2_[8];
    float dsum = 0.0f;
    #pragma unroll
    for (int u = 0; u < 8; ++u) {
        int k = u * LPQ + l;
        bool v = (k < (int)sc);
        int j = v ? (int)(selk[g*32 + k] & 0xFFFFu) : 0;
        float4 sp = A[j];
        float4 nn = B[j];
        float px = qx - sp.x, py = qy - sp.y, pz = qz - sp.z;
        float r2 = px*px + py*py + pz*pz;
        float m = v ? 1.0f : 0.0f;
        px_[u] = px * m; py_[u] = py * m; pz_[u] = pz * m;
        nx_[u] = nn.x * m; ny_[u] = nn.y * m; nz_[u] = nn.z * m;
        r2_[u] = r2 * m;
        fx_[u] = px_[u]*nx_[u] + py_[u]*ny_[u] + pz_[u]*nz_[u];
        dsum += v ? sqrtf(r2) : 0.0f;
        phi_[u] = m;
    }
    dsum += __shfl_xor(dsum, 1, LPQ);
    dsum += __shfl_xor(dsum, 2, LPQ);
    float h = dsum * (1.0f / (float)KNN) + 1e-8f;
    float h2 = h * h;
    float c8 = -8.0f / h2;
    #pragma unroll
    for (int u = 0; u < 8; ++u) {
        float tt = fmaxf(1.0f - r2_[u] / h2, 0.0f);
        float t2 = tt * tt;
        float valid = phi_[u];
        phi_[u] = t2 * t2 * valid;
        gco_[u] = c8 * t2 * tt * valid;
    }

    const float inv_sn2 = 1.0f / (SIGMA_N * SIGMA_N);
    float f = 0.0f, gx = 0.0f, gy = 0.0f, gz = 0.0f;
    bool done = false;
    for (int it = 0; it < 3; ++it) {
        if (done) break;
        float sw=0, swf=0, sgx=0, sgy=0, sgz=0, sfx=0, sfy=0, sfz=0, snx=0, sny=0, snz=0;
        #pragma unroll
        for (int u = 0; u < 8; ++u) {
            float alpha = 1.0f;
            if (it > 0) {
                float dx = nx_[u]-gx, dy = ny_[u]-gy, dz = nz_[u]-gz;
                alpha = expf(-(dx*dx + dy*dy + dz*dz) * inv_sn2);
            }
            float w = alpha * phi_[u];
            float gg = alpha * gco_[u];
            float gf = gg * fx_[u];
            sw  += w;          swf += w * fx_[u];
            sgx += gg*px_[u];  sgy += gg*py_[u];  sgz += gg*pz_[u];
            sfx += gf*px_[u];  sfy += gf*py_[u];  sfz += gf*pz_[u];
            snx += w*nx_[u];   sny += w*ny_[u];   snz += w*nz_[u];
        }
        #pragma unroll
        for (int m = 1; m < LPQ; m <<= 1) {
            sw  += __shfl_xor(sw, m, LPQ);  swf += __shfl_xor(swf, m, LPQ);
            sgx += __shfl_xor(sgx, m, LPQ); sgy += __shfl_xor(sgy, m, LPQ); sgz += __shfl_xor(sgz, m, LPQ);
            sfx += __shfl_xor(sfx, m, LPQ); sfy += __shfl_xor(sfy, m, LPQ); sfz += __shfl_xor(sfz, m, LPQ);
            snx += __shfl_xor(snx, m, LPQ); sny += __shfl_xor(sny, m, LPQ); snz += __shfl_xor(snz, m, LPQ);
        }
        sw += 1e-8f;
        float fn  = swf / sw;
        float gnx = (sfx + snx - fn*sgx) / sw;
        float gny = (sfy + sny - fn*sgy) / sw;
        float gnz = (sfz + snz - fn*sgz) / sw;
        done = (fabsf(fn - f) < THRESHV);
        f = fn; gx = gnx; gy = gny; gz = gnz;
    }
    if (l == 0 && vq) {
        out[gq] = f;
        out[N + 3*gq + 0] = gx;
        out[N + 3*gq + 1] = gy;
        out[N + 3*gq + 2] = gz;
    }
}

// ======================= fallback: R2 brute force =======================

#define QT 32
#define NTH 256
#define CAP 160
#define CAPS 161
#define RSEL 20

__global__ void prep_pack(const float* __restrict__ src, float4* __restrict__ dst, int M) {
    int j = blockIdx.x * 256 + threadIdx.x;
    if (j < M) {
        float x = src[3*j+0], y = src[3*j+1], z = src[3*j+2];
        dst[j] = make_float4(x, y, z, 0.5f*(x*x + y*y + z*z));
    }
}

template<bool PACKED>
__device__ __forceinline__ float4 fetch_pt(const float4* __restrict__ sp,
                                           const float* __restrict__ sv, int j) {
    if (PACKED) return sp[j];
    float x = sv[3*j+0], y = sv[3*j+1], z = sv[3*j+2];
    return make_float4(x, y, z, 0.5f*(x*x + y*y + z*z));
}

__device__ __forceinline__ void ins4b(unsigned int k, unsigned int &m0, unsigned int &m1,
                                      unsigned int &m2, unsigned int &m3) {
    if (k < m3) {
        if (k < m2) {
            m3 = m2;
            if (k < m1) { m2 = m1; if (k < m0) { m1 = m0; m0 = k; } else m1 = k; }
            else m2 = k;
        } else m3 = k;
    }
}

template<bool PACKED>
__global__ __launch_bounds__(NTH)
void rimls_fused(const float* __restrict__ qpts,
                 const float* __restrict__ sverts,
                 const float* __restrict__ snorms,
                 const float4* __restrict__ spack,
                 float* __restrict__ out,
                 int N, int M)
{
    __shared__ unsigned int cand[QT * CAPS];
    __shared__ unsigned int selk[QT * KNN];
    __shared__ float4 qbuf[QT];
    __shared__ unsigned int cnt[QT];
    __shared__ unsigned int T16[QT];
    __shared__ int retryq[QT];

    const int t  = threadIdx.x;
    const int qg = t >> 4;
    const int c  = t & 15;
    const int qa = qg, qb = qg + 16;

    if (t < QT) {
        int gq = blockIdx.x * QT + t; if (gq >= N) gq = N - 1;
        float x = qpts[3*gq+0], y = qpts[3*gq+1], z = qpts[3*gq+2];
        qbuf[t] = make_float4(x, y, z, 0.5f*(x*x + y*y + z*z));
    }
    for (int i = t; i < QT * KNN; i += NTH) selk[i] = 0u;
    __syncthreads();

    const float ax = qbuf[qa].x, ay = qbuf[qa].y, az = qbuf[qa].z, aw = qbuf[qa].w;
    const float bx = qbuf[qb].x, by = qbuf[qb].y, bz = qbuf[qb].z, bw = qbuf[qb].w;

    unsigned int a0=~0u,a1=~0u,a2=~0u,a3=~0u, b0=~0u,b1=~0u,b2=~0u,b3=~0u;
    {
        const int n1 = M >> 6;
        #pragma unroll 2
        for (int i = 0; i < n1; ++i) {
            int j = (c + (i << 4)) << 2;
            float4 s = fetch_pt<PACKED>(spack, sverts, j);
            float va = fmaxf(fmaf(-ax, s.x, fmaf(-ay, s.y, fmaf(-az, s.z, s.w + aw))), 0.0f);
            float vb = fmaxf(fmaf(-bx, s.x, fmaf(-by, s.y, fmaf(-bz, s.z, s.w + bw))), 0.0f);
            unsigned int ka = (__float_as_uint(va) & 0xFFFF0000u) | (unsigned int)j;
            unsigned int kb = (__float_as_uint(vb) & 0xFFFF0000u) | (unsigned int)j;
            ins4b(ka, a0, a1, a2, a3);
            ins4b(kb, b0, b1, b2, b3);
        }
    }
    {
        unsigned int* mb = cand;
        mb[qa*64 + c*4 + 0] = a0; mb[qa*64 + c*4 + 1] = a1;
        mb[qa*64 + c*4 + 2] = a2; mb[qa*64 + c*4 + 3] = a3;
        mb[qb*64 + c*4 + 0] = b0; mb[qb*64 + c*4 + 1] = b1;
        mb[qb*64 + c*4 + 2] = b2; mb[qb*64 + c*4 + 3] = b3;
    }
    __syncthreads();
    if (t < QT) {
        const unsigned int* m_ = cand + t * 64;
        unsigned int kth = 0xFFFFFFFFu;
        for (int a = 0; a < 64; ++a) {
            unsigned int ka = m_[a]; int r = 0;
            for (int b = 0; b < 64; ++b) r += (m_[b] < ka) ? 1 : 0;
            if (r == RSEL - 1) kth = ka;
        }
        unsigned int tb = (kth >> 16) + 1u;
        if (tb > 0x7F00u) tb = 0x7F00u;
        T16[t] = tb; cnt[t] = 0u; retryq[t] = 1;
    }
    __syncthreads();

    const int n3 = M >> 4;
    for (int round = 0; round < 8; ++round) {
        bool aa = retryq[qa] != 0, ab = retryq[qb] != 0;
        if (aa || ab) {
            float Ta = aa ? __uint_as_float(T16[qa] << 16) : 0.0f;
            float Tb = ab ? __uint_as_float(T16[qb] << 16) : 0.0f;
            #pragma unroll 4
            for (int i = 0; i < n3; ++i) {
                int j = c + (i << 4);
                float4 s = fetch_pt<PACKED>(spack, sverts, j);
                float va = fmaxf(fmaf(-ax, s.x, fmaf(-ay, s.y, fmaf(-az, s.z, s.w + aw))), 0.0f);
                float vb = fmaxf(fmaf(-bx, s.x, fmaf(-by, s.y, fmaf(-bz, s.z, s.w + bw))), 0.0f);
                if (va < Ta) {
                    unsigned int pos = atomicAdd(&cnt[qa], 1u);
                    if (pos < (unsigned)CAP)
                        cand[qa*CAPS + pos] = (__float_as_uint(va) & 0xFFFF0000u) | (unsigned int)j;
                }
                if (vb < Tb) {
                    unsigned int pos = atomicAdd(&cnt[qb], 1u);
                    if (pos < (unsigned)CAP)
                        cand[qb*CAPS + pos] = (__float_as_uint(vb) & 0xFFFF0000u) | (unsigned int)j;
                }
            }
        }
        __syncthreads();
        int bad = 0;
        if (t < QT && retryq[t]) {
            unsigned int cc = cnt[t], tb = T16[t];
            if (cc < (unsigned)KNN) {
                if (tb < 0x7F00u) {
                    tb += (1u << 7);
                    if (tb > 0x7F00u) tb = 0x7F00u;
                    bad = 1;
                }
            } else if (cc > (unsigned)CAP && round < 4 && tb > (1u << 6)) {
                tb -= (1u << 6); bad = 1;
            }
            if (bad) { T16[t] = tb; cnt[t] = 0u; }
            else retryq[t] = 0;
        }
        if (!__syncthreads_or(bad)) break;
    }

    const int qs = t >> 3, s8 = t & 7;
    {
        unsigned int cc = cnt[qs];
        int C = (int)(cc < (unsigned)CAP ? cc : (unsigned)CAP);
        const unsigned int* cd = cand + qs * CAPS;
        for (int a = s8; a < C; a += 8) {
            unsigned int ka = cd[a]; int r = 0;
            for (int b = 0; b < C; ++b) r += (cd[b] < ka) ? 1 : 0;
            if (r < KNN) selk[qs*KNN + r] = ka;
        }
    }
    __syncthreads();

    {
        const float qx = qbuf[qs].x, qy = qbuf[qs].y, qz = qbuf[qs].z;
        float px_[4], py_[4], pz_[4], nx_[4], ny_[4], nz_[4];
        float fx_[4], phi_[4], gco_[4], r2_[4];
        float dsum = 0.0f;
        #pragma unroll
        for (int u = 0; u < 4; ++u) {
            int k = s8 + 8*u;
            bool v = (k < KNN);
            int j = v ? (int)(selk[qs*KNN + k] & 0xFFFFu) : 0;
            float4 s = fetch_pt<PACKED>(spack, sverts, j);
            float px = qx - s.x, py = qy - s.y, pz = qz - s.z;
            float r2 = px*px + py*py + pz*pz;
            float nx = snorms[3*j+0], ny = snorms[3*j+1], nz = snorms[3*j+2];
            float nrm = sqrtf(nx*nx + ny*ny + nz*nz);
            float inv = 1.0f / fmaxf(nrm, 1e-8f);
            float m = v ? 1.0f : 0.0f;
            nx *= inv * m; ny *= inv * m; nz *= inv * m;
            px_[u] = px * m; py_[u] = py * m; pz_[u] = pz * m;
            nx_[u] = nx; ny_[u] = ny; nz_[u] = nz;
            r2_[u] = r2 * m;
            fx_[u] = px_[u]*nx + py_[u]*ny + pz_[u]*nz;
            dsum += v ? sqrtf(r2) : 0.0f;
            phi_[u] = m;
        }
        dsum += __shfl_xor(dsum, 1);
        dsum += __shfl_xor(dsum, 2);
        dsum += __shfl_xor(dsum, 4);
        float h = dsum * (1.0f / (float)KNN) + 1e-8f;
        float h2 = h * h;
        float c8 = -8.0f / h2;
        #pragma unroll
        for (int u = 0; u < 4; ++u) {
            float tt = fmaxf(1.0f - r2_[u] / h2, 0.0f);
            float t2 = tt * tt;
            float valid = phi_[u];
            phi_[u] = t2 * t2 * valid;
            gco_[u] = c8 * t2 * tt * valid;
        }

        const float inv_sn2 = 1.0f / (SIGMA_N * SIGMA_N);
        float f = 0.0f, gx = 0.0f, gy = 0.0f, gz = 0.0f;
        bool done = false;
        for (int it = 0; it < 3; ++it) {
            if (done) break;
            float sw=0, swf=0, sgx=0, sgy=0, sgz=0, sfx=0, sfy=0, sfz=0, snx=0, sny=0, snz=0;
            #pragma unroll
            for (int u = 0; u < 4; ++u) {
                float alpha = 1.0f;
                if (it > 0) {
                    float dx = nx_[u]-gx, dy = ny_[u]-gy, dz = nz_[u]-gz;
                    alpha = expf(-(dx*dx + dy*dy + dz*dz) * inv_sn2);
                }
                float w = alpha * phi_[u];
                float g = alpha * gco_[u];
                float gf = g * fx_[u];
                sw  += w;          swf += w * fx_[u];
                sgx += g*px_[u];   sgy += g*py_[u];   sgz += g*pz_[u];
                sfx += gf*px_[u];  sfy += gf*py_[u];  sfz += gf*pz_[u];
                snx += w*nx_[u];   sny += w*ny_[u];   snz += w*nz_[u];
            }
            #pragma unroll
            for (int m = 1; m < 8; m <<= 1) {
                sw  += __shfl_xor(sw, m);  swf += __shfl_xor(swf, m);
                sgx += __shfl_xor(sgx, m); sgy += __shfl_xor(sgy, m); sgz += __shfl_xor(sgz, m);
                sfx += __shfl_xor(sfx, m); sfy += __shfl_xor(sfy, m); sfz += __shfl_xor(sfz, m);
                snx += __shfl_xor(snx, m); sny += __shfl_xor(sny, m); snz += __shfl_xor(snz, m);
            }
            sw += 1e-8f;
            float fn  = swf / sw;
            float gnx = (sfx + snx - fn*sgx) / sw;
            float gny = (sfy + sny - fn*sgy) / sw;
            float gnz = (sfz + snz - fn*sgz) / sw;
            float delta = fabsf(fn - f);
            f = fn; gx = gnx; gy = gny; gz = gnz;
            done = (delta < THRESHV);
        }
        if (s8 == 0) {
            int gq = blockIdx.x * QT + qs;
            if (gq < N) {
                out[gq] = f;
                out[N + 3*gq + 0] = gx;
                out[N + 3*gq + 1] = gy;
                out[N + 3*gq + 2] = gz;
            }
        }
    }
}

// ======================= launcher =======================

extern "C" void kernel_launch(void* const* d_in, const int* in_sizes, int n_in,
                              void* d_out, int out_size, void* d_ws, size_t ws_size,
                              hipStream_t stream) {
    (void)n_in; (void)out_size;
    const float* qpts   = (const float*)d_in[0];
    const float* sverts = (const float*)d_in[1];
    const float* snorms = (const float*)d_in[2];
    float* out = (float*)d_out;
    int N = in_sizes[0] / 3;
    int M = in_sizes[1] / 3;

    if (ws_size >= (size_t)WS_NEED && M <= 65536 && N <= 65536) {
        char* ws = (char*)d_ws;
        float4*   A    = (float4*)(ws + OFF_A);
        float4*   B    = (float4*)(ws + OFF_B);
        unsigned* cs   = (unsigned*)(ws + OFF_CS);
        unsigned* cur  = (unsigned*)(ws + OFF_CUR);
        unsigned* pc   = (unsigned*)(ws + OFF_PC);
        unsigned* bs   = (unsigned*)(ws + OFF_BS);
        unsigned* qcs  = (unsigned*)(ws + OFF_QCS);
        unsigned* qord = (unsigned*)(ws + OFF_QORD);

        zero_u32<<<(NC + 1 + 255) / 256, 256, 0, stream>>>(cs, NC + 1);
        grid_count<<<(M + 255) / 256, 256, 0, stream>>>(sverts, cs, pc, M);
        scan1<<<256, 256, 0, stream>>>(cs, bs);
        scan2<<<1, 256, 0, stream>>>(bs);
        scan3<<<256, 256, 0, stream>>>(cs, cur, bs, (unsigned)M);
        grid_scatter<<<(M + 255) / 256, 256, 0, stream>>>(sverts, snorms, pc, cur, A, B, M);
        zero_u32<<<(NC + 1 + 255) / 256, 256, 0, stream>>>(qcs, NC + 1);
        grid_count<<<(N + 255) / 256, 256, 0, stream>>>(qpts, qcs, pc, N);
        scan1<<<256, 256, 0, stream>>>(qcs, bs);
        scan2<<<1, 256, 0, stream>>>(bs);
        scan3<<<256, 256, 0, stream>>>(qcs, cur, bs, (unsigned)N);
        qscatter<<<(N + 255) / 256, 256, 0, stream>>>(pc, cur, qord, N);
        knn_rimls4<<<(N + QPB - 1) / QPB, 256, 0, stream>>>(qpts, A, B, cs, qord, out, N);
    } else if (ws_size >= (size_t)M * sizeof(float4)) {
        float4* spack = (float4*)d_ws;
        prep_pack<<<(M + 255) / 256, 256, 0, stream>>>(sverts, spack, M);
        rimls_fused<true><<<(N + QT - 1) / QT, NTH, 0, stream>>>(qpts, sverts, snorms, spack, out, N, M);
    } else {
        rimls_fused<false><<<(N + QT - 1) / QT, NTH, 0, stream>>>(qpts, sverts, snorms, nullptr, out, N, M);
    }
}